// Round 7
// baseline (87.249 us; speedup 1.0000x reference)
//
#include <hip/hip_runtime.h>

#define NB    4
#define PPB   4096           // downsampled points per batch (64x64)
#define BLK   256
#define NBLK2 2080           // triangle blocks per batch over 64-chunks: 64*65/2
#define NPART (NBLK2 * NB)   // 8320 partials

#if __has_builtin(__builtin_amdgcn_exp2f)
#define EXPFN(x) __builtin_amdgcn_exp2f(x)
#define FSCALE 1.2011224087864498f   /* sqrt(log2(e)) */
#else
#define EXPFN(x) __expf(x)
#define FSCALE 1.0f
#endif

typedef __attribute__((ext_vector_type(8))) short short8v;   // 8 bf16 (4 VGPR)
typedef __attribute__((ext_vector_type(4))) float f32x4;

typedef unsigned int uint;
typedef unsigned short ushort;

// Round-to-nearest-even bf16 split: returns bf16 bits, rem = v - bf16(v) (exact).
__device__ __forceinline__ ushort bsplit(float v, float& rem) {
    uint u = __float_as_uint(v);
    uint r = (u + 0x7FFFu + ((u >> 16) & 1u)) >> 16;
    rem = v - __uint_as_float(r << 16);
    return (ushort)r;
}

// ws layout (per 16384 global points):
//   FA[p][32] bf16  feat K-vector, A-pattern [f1 f1 f2 f1 f2 f3 | 0 0]
//   FB[p][32] bf16  feat K-vector, B-pattern [f1 f2 f1 f3 f2 f1 | 0 0]
//   SA[p][32] bf16  seg  K-vector, A-pattern [t1 t1 t2 | 0...]
//   SB[p][32] bf16  seg  K-vector, B-pattern [t1 t2 t1 | 0...]
//   H [p]     f32   h = -0.5*|f^|^2 (log2 units; f^ = f*FSCALE)
// gram(p,q) = sum_k FA[p][k]*FB[q][k] ~= f^_p . f^_q  (err ~|g|*2^-26)
// SC(p,q)   = sum_k SA[p][k]*SB[q][k] ~= s_p . s_q    (err ~2^-18)
__global__ __launch_bounds__(256) void crf_prep(const float* __restrict__ images,
                                                const float* __restrict__ segs,
                                                uint* __restrict__ FA,
                                                uint* __restrict__ FB,
                                                uint* __restrict__ SA,
                                                uint* __restrict__ SB,
                                                float* __restrict__ H) {
    int gid = blockIdx.x * BLK + threadIdx.x;   // 0..16383
    int n = gid >> 12;
    int p = gid & (PPB - 1);
    int i = p >> 6;
    int j = p & 63;
    int off = 256 * i + 2 * j;                  // pixel (2i,2j) in 128x128
    const float* img = images + (size_t)n * 3 * 16384;
    float f[5];
    f[0] = (float)j * (FSCALE / 50.0f);         // SIGMA_XY*SCALE = 50
    f[1] = (float)i * (FSCALE / 50.0f);
    f[2] = img[off]         * (FSCALE / 15.0f); // SIGMA_RGB = 15
    f[3] = img[16384 + off] * (FSCALE / 15.0f);
    f[4] = img[32768 + off] * (FSCALE / 15.0f);
    float h = -0.5f * (f[0]*f[0] + f[1]*f[1] + f[2]*f[2] + f[3]*f[3] + f[4]*f[4]);

    const float* sg = segs + (size_t)n * 4 * 16384;
    float s[4];
#pragma unroll
    for (int k = 0; k < 4; ++k) {
        float2 u0 = *(const float2*)(sg + k * 16384 + off);
        float2 u1 = *(const float2*)(sg + k * 16384 + off + 128);
        s[k] = 0.25f * ((u0.x + u0.y) + (u1.x + u1.y));
    }

    // 3-way bf16 split of feats, 2-way split of segs.
    ushort v[3][5];
    ushort tg[2][4];
#pragma unroll
    for (int c = 0; c < 5; ++c) {
        float r1, r2, dead;
        v[0][c] = bsplit(f[c], r1);
        v[1][c] = bsplit(r1, r2);
        v[2][c] = bsplit(r2, dead);
    }
#pragma unroll
    for (int c = 0; c < 4; ++c) {
        float r1, dead;
        tg[0][c] = bsplit(s[c], r1);
        tg[1][c] = bsplit(r1, dead);
    }

    static const int PA[6] = {0, 0, 1, 0, 1, 2};
    static const int PB[6] = {0, 1, 0, 2, 1, 0};
    uint* fap = FA + (size_t)gid * 16;
    uint* fbp = FB + (size_t)gid * 16;
#pragma unroll
    for (int k2 = 0; k2 < 16; ++k2) {
        int s0 = 2 * k2, s1 = s0 + 1;
        uint lo = (s0 >= 30) ? 0u : (uint)v[PA[s0 / 5]][s0 % 5];
        uint hi = (s1 >= 30) ? 0u : (uint)v[PA[s1 / 5]][s1 % 5];
        fap[k2] = lo | (hi << 16);
        lo = (s0 >= 30) ? 0u : (uint)v[PB[s0 / 5]][s0 % 5];
        hi = (s1 >= 30) ? 0u : (uint)v[PB[s1 / 5]][s1 % 5];
        fbp[k2] = lo | (hi << 16);
    }
    static const int QA[3] = {0, 0, 1};
    static const int QB[3] = {0, 1, 0};
    uint* sap = SA + (size_t)gid * 16;
    uint* sbp = SB + (size_t)gid * 16;
#pragma unroll
    for (int k2 = 0; k2 < 16; ++k2) {
        int s0 = 2 * k2, s1 = s0 + 1;
        uint lo = (s0 >= 12) ? 0u : (uint)tg[QA[s0 / 4]][s0 % 4];
        uint hi = (s1 >= 12) ? 0u : (uint)tg[QA[s1 / 4]][s1 % 4];
        sap[k2] = lo | (hi << 16);
        lo = (s0 >= 12) ? 0u : (uint)tg[QB[s0 / 4]][s0 % 4];
        hi = (s1 >= 12) ? 0u : (uint)tg[QB[s1 / 4]][s1 % 4];
        sbp[k2] = lo | (hi << 16);
    }
    H[gid] = h;
}

// MFMA pair kernel: per 16x16 tile, one MFMA computes the 5-dim feature gram
// (split-bf16, fp32-accurate) and one computes the seg-dot gram. Per-pair VALU
// = 2 add + exp2 + 1 fma. Triangle over 64-chunks; diagonal tiles weighted
// 2/1/0 in-register. grid = (2080, 4), 4 waves/block, wave = one 16p M-tile.
__global__ __launch_bounds__(256, 6) void crf_pairs(const uint4* __restrict__ FA,
                                                    const uint4* __restrict__ FB,
                                                    const uint4* __restrict__ SA,
                                                    const uint4* __restrict__ SB,
                                                    const float* __restrict__ H,
                                                    float* __restrict__ part) {
    __shared__ float wsum[BLK / 64];
    int t = threadIdx.x;
    int n = blockIdx.y;
    int lane = t & 63;
    int w = t >> 6;
    int l15 = lane & 15;
    int lhi = lane >> 4;

    // Decode triangle block -> (p-chunk pc, q-chunk qc), 64-point chunks,
    // qc >= pc.  cum(pc) = 64*pc - pc*(pc-1)/2
    int b = blockIdx.x;                  // 0..2079
    int pc = 0;
#pragma unroll
    for (int i = 1; i < 64; ++i) pc += (b >= (64 * i - (i * (i - 1)) / 2)) ? 1 : 0;
    int qc = b - (64 * pc - (pc * (pc - 1)) / 2) + pc;
    bool diagblk = (pc == qc);
    int base = n << 12;
    int prow0 = pc * 64 + w * 16;        // wave's M-tile (16 p-points)

    // A-side fragments (resident for the whole block).
    size_t arow = (size_t)(base + prow0 + l15) * 4 + lhi;
    short8v afrag = __builtin_bit_cast(short8v, FA[arow]);
    short8v safrag = __builtin_bit_cast(short8v, SA[arow]);
    float hp[4];
#pragma unroll
    for (int r = 0; r < 4; ++r)
        hp[r] = H[base + prow0 + lhi * 4 + r];

    float accP = 0.f;   // plain tiles (doubled at the end)
    float accD = 0.f;   // diagonal tiles (explicit 2/1/0 weights)

#pragma unroll
    for (int jj = 0; jj < 4; ++jj) {
        if (diagblk && jj < w) continue;     // lower-triangle tiles skipped
        int qrow0 = qc * 64 + jj * 16;
        size_t brow = (size_t)(base + qrow0 + l15) * 4 + lhi;
        short8v bfrag = __builtin_bit_cast(short8v, FB[brow]);
        short8v sbfrag = __builtin_bit_cast(short8v, SB[brow]);
        float hq = H[base + qrow0 + l15];

        f32x4 cf = {0.f, 0.f, 0.f, 0.f};
        f32x4 cs = {0.f, 0.f, 0.f, 0.f};
        cf = __builtin_amdgcn_mfma_f32_16x16x32_bf16(afrag, bfrag, cf, 0, 0, 0);
        cs = __builtin_amdgcn_mfma_f32_16x16x32_bf16(safrag, sbfrag, cs, 0, 0, 0);

        if (diagblk && jj == w) {
            // Tile on the diagonal: weight 2 / 1 / 0 for col>row / == / <.
#pragma unroll
            for (int r = 0; r < 4; ++r) {
                float d = cf[r] + (hp[r] + hq);
                float wg = EXPFN(d);
                int pg = lhi * 4 + r;
                float fw = (l15 > pg) ? 2.0f : ((l15 == pg) ? 1.0f : 0.0f);
                accD = fmaf(wg * fw, cs[r], accD);
            }
        } else {
#pragma unroll
            for (int r = 0; r < 4; ++r) {
                float d = cf[r] + (hp[r] + hq);
                float wg = EXPFN(d);
                accP = fmaf(wg, cs[r], accP);
            }
        }
    }

    float acc_all = 2.0f * accP + accD;
#pragma unroll
    for (int off = 32; off > 0; off >>= 1)
        acc_all += __shfl_down(acc_all, off, 64);
    if ((t & 63) == 0) wsum[t >> 6] = acc_all;
    __syncthreads();
    if (t == 0) {
        part[n * NBLK2 + blockIdx.x] =
            (wsum[0] + wsum[1]) + (wsum[2] + wsum[3]);
    }
}

// Final reduction: 8320 partials -> out[0], single block, no atomics.
__global__ __launch_bounds__(256) void crf_reduce(const float* __restrict__ part,
                                                  float* __restrict__ out) {
    __shared__ float wsum[BLK / 64];
    int t = threadIdx.x;
    float s = 0.f;
#pragma unroll
    for (int i = 0; i < 33; ++i) {
        int idx = t + i * BLK;
        if (idx < NPART) s += part[idx];
    }
#pragma unroll
    for (int off = 32; off > 0; off >>= 1)
        s += __shfl_down(s, off, 64);
    if ((t & 63) == 0) wsum[t >> 6] = s;
    __syncthreads();
    if (t == 0) {
        float tot = (wsum[0] + wsum[1]) + (wsum[2] + wsum[3]);
        // loss = WEIGHT * (-sum / n) = -1e-7/4 * sum
        out[0] = tot * (-2.5e-8f);
    }
}

extern "C" void kernel_launch(void* const* d_in, const int* in_sizes, int n_in,
                              void* d_out, int out_size, void* d_ws, size_t ws_size,
                              hipStream_t stream) {
    const float* images = (const float*)d_in[0];
    const float* segs   = (const float*)d_in[1];
    float* out = (float*)d_out;
    char* ws = (char*)d_ws;
    uint* FA = (uint*)(ws);                     // 16384*64 B = 1 MiB
    uint* FB = (uint*)(ws + (1u << 20));        // 1 MiB
    uint* SA = (uint*)(ws + (2u << 20));        // 1 MiB
    uint* SB = (uint*)(ws + (3u << 20));        // 1 MiB
    float* H = (float*)(ws + (4u << 20));       // 64 KiB
    float* part = (float*)(ws + (4u << 20) + 65536);  // 8320*4 B
    (void)in_sizes; (void)n_in; (void)out_size; (void)ws_size;

    crf_prep<<<dim3(64), dim3(256), 0, stream>>>(images, segs, FA, FB, SA, SB, H);
    crf_pairs<<<dim3(NBLK2, NB), dim3(256), 0, stream>>>(
        (const uint4*)FA, (const uint4*)FB, (const uint4*)SA, (const uint4*)SB, H, part);
    crf_reduce<<<dim3(1), dim3(256), 0, stream>>>(part, out);
}

// Round 8
// 80.407 us; speedup vs baseline: 1.0851x; 1.0851x over previous
//
#include <hip/hip_runtime.h>

#define NB    4
#define PPB   4096           // downsampled points per batch (64x64)
#define BLK   256
#define CHK   128            // points per triangle chunk
#define NCHK  32             // chunks per batch
#define NBLK3 528            // triangle blocks per batch: 32*33/2
#define NPART (NBLK3 * NB)   // 2112 partials

#if __has_builtin(__builtin_amdgcn_exp2f)
#define EXPFN(x) __builtin_amdgcn_exp2f(x)
#define FSCALE 1.2011224087864498f   /* sqrt(log2(e)) */
#else
#define EXPFN(x) __expf(x)
#define FSCALE 1.0f
#endif

typedef __attribute__((ext_vector_type(8))) short short8v;   // 8 bf16 (4 VGPR)
typedef __attribute__((ext_vector_type(4))) float f32x4;

typedef unsigned int uint;
typedef unsigned short ushort;

// Round-to-nearest-even bf16 split: returns bf16 bits, rem = v - bf16(v) (exact).
__device__ __forceinline__ ushort bsplit(float v, float& rem) {
    uint u = __float_as_uint(v);
    uint r = (u + 0x7FFFu + ((u >> 16) & 1u)) >> 16;
    rem = v - __uint_as_float(r << 16);
    return (ushort)r;
}

// ws layout (per 16384 global points) -- identical packing to the
// HW-verified R7 kernel (absmax 0.0):
//   FA[p][32] bf16  feat K-vector, A-pattern [f1 f1 f2 f1 f2 f3 | 0 0]
//   FB[p][32] bf16  feat K-vector, B-pattern [f1 f2 f1 f3 f2 f1 | 0 0]
//   SA[p][32] bf16  seg  K-vector, A-pattern [t1 t1 t2 | 0...]
//   SB[p][32] bf16  seg  K-vector, B-pattern [t1 t2 t1 | 0...]
//   H [p]     f32   h = -0.5*|f^|^2 (log2 units; f^ = f*FSCALE)
__global__ __launch_bounds__(256) void crf_prep(const float* __restrict__ images,
                                                const float* __restrict__ segs,
                                                uint* __restrict__ FA,
                                                uint* __restrict__ FB,
                                                uint* __restrict__ SA,
                                                uint* __restrict__ SB,
                                                float* __restrict__ H) {
    int gid = blockIdx.x * BLK + threadIdx.x;   // 0..16383
    int n = gid >> 12;
    int p = gid & (PPB - 1);
    int i = p >> 6;
    int j = p & 63;
    int off = 256 * i + 2 * j;                  // pixel (2i,2j) in 128x128
    const float* img = images + (size_t)n * 3 * 16384;
    float f[5];
    f[0] = (float)j * (FSCALE / 50.0f);         // SIGMA_XY*SCALE = 50
    f[1] = (float)i * (FSCALE / 50.0f);
    f[2] = img[off]         * (FSCALE / 15.0f); // SIGMA_RGB = 15
    f[3] = img[16384 + off] * (FSCALE / 15.0f);
    f[4] = img[32768 + off] * (FSCALE / 15.0f);
    float h = -0.5f * (f[0]*f[0] + f[1]*f[1] + f[2]*f[2] + f[3]*f[3] + f[4]*f[4]);

    const float* sg = segs + (size_t)n * 4 * 16384;
    float s[4];
#pragma unroll
    for (int k = 0; k < 4; ++k) {
        float2 u0 = *(const float2*)(sg + k * 16384 + off);
        float2 u1 = *(const float2*)(sg + k * 16384 + off + 128);
        s[k] = 0.25f * ((u0.x + u0.y) + (u1.x + u1.y));
    }

    // 3-way bf16 split of feats, 2-way split of segs.
    ushort v[3][5];
    ushort tg[2][4];
#pragma unroll
    for (int c = 0; c < 5; ++c) {
        float r1, r2, dead;
        v[0][c] = bsplit(f[c], r1);
        v[1][c] = bsplit(r1, r2);
        v[2][c] = bsplit(r2, dead);
    }
#pragma unroll
    for (int c = 0; c < 4; ++c) {
        float r1, dead;
        tg[0][c] = bsplit(s[c], r1);
        tg[1][c] = bsplit(r1, dead);
    }

    static const int PA[6] = {0, 0, 1, 0, 1, 2};
    static const int PB[6] = {0, 1, 0, 2, 1, 0};
    uint fa[16], fb[16], sa[16], sb[16];
#pragma unroll
    for (int k2 = 0; k2 < 16; ++k2) {
        int s0 = 2 * k2, s1 = s0 + 1;
        uint lo = (s0 >= 30) ? 0u : (uint)v[PA[s0 / 5]][s0 % 5];
        uint hi = (s1 >= 30) ? 0u : (uint)v[PA[s1 / 5]][s1 % 5];
        fa[k2] = lo | (hi << 16);
        lo = (s0 >= 30) ? 0u : (uint)v[PB[s0 / 5]][s0 % 5];
        hi = (s1 >= 30) ? 0u : (uint)v[PB[s1 / 5]][s1 % 5];
        fb[k2] = lo | (hi << 16);
    }
    static const int QA[3] = {0, 0, 1};
    static const int QB[3] = {0, 1, 0};
#pragma unroll
    for (int k2 = 0; k2 < 16; ++k2) {
        int s0 = 2 * k2, s1 = s0 + 1;
        uint lo = (s0 >= 12) ? 0u : (uint)tg[QA[s0 / 4]][s0 % 4];
        uint hi = (s1 >= 12) ? 0u : (uint)tg[QA[s1 / 4]][s1 % 4];
        sa[k2] = lo | (hi << 16);
        lo = (s0 >= 12) ? 0u : (uint)tg[QB[s0 / 4]][s0 % 4];
        hi = (s1 >= 12) ? 0u : (uint)tg[QB[s1 / 4]][s1 % 4];
        sb[k2] = lo | (hi << 16);
    }

    // Vectorized stores: 16x store_dwordx4 instead of 64x store_dword.
    uint4* fap = (uint4*)(FA + (size_t)gid * 16);
    uint4* fbp = (uint4*)(FB + (size_t)gid * 16);
    uint4* sap = (uint4*)(SA + (size_t)gid * 16);
    uint4* sbp = (uint4*)(SB + (size_t)gid * 16);
#pragma unroll
    for (int k = 0; k < 4; ++k) {
        fap[k] = make_uint4(fa[4*k], fa[4*k+1], fa[4*k+2], fa[4*k+3]);
        fbp[k] = make_uint4(fb[4*k], fb[4*k+1], fb[4*k+2], fb[4*k+3]);
        sap[k] = make_uint4(sa[4*k], sa[4*k+1], sa[4*k+2], sa[4*k+3]);
        sbp[k] = make_uint4(sb[4*k], sb[4*k+1], sb[4*k+2], sb[4*k+3]);
    }
    H[gid] = h;
}

// MFMA pair kernel, amortized: 128x128-point chunks, 4 waves/block, each wave
// holds TWO resident A-fragment pairs (32 p-rows) and loops 8 q-tiles; each
// B-fragment load feeds 4 MFMAs. grid = (528 triangle chunks, 4 batches).
__global__ __launch_bounds__(256, 4) void crf_pairs(const uint4* __restrict__ FA,
                                                    const uint4* __restrict__ FB,
                                                    const uint4* __restrict__ SA,
                                                    const uint4* __restrict__ SB,
                                                    const float* __restrict__ H,
                                                    float* __restrict__ part) {
    __shared__ float wsum[BLK / 64];
    int t = threadIdx.x;
    int n = blockIdx.y;
    int lane = t & 63;
    int w = t >> 6;
    int l15 = lane & 15;
    int lhi = lane >> 4;

    // Decode triangle block -> (p-chunk pc, q-chunk qc), qc >= pc.
    // cum(pc) = pc*(2*NCHK+1-pc)/2
    int b = blockIdx.x;                  // 0..527
    int pc = 0;
#pragma unroll
    for (int i = 1; i < NCHK; ++i) pc += (b >= (i * (2 * NCHK + 1 - i)) / 2) ? 1 : 0;
    int qc = b - (pc * (2 * NCHK + 1 - pc)) / 2 + pc;
    bool diagblk = (pc == qc);
    int base = n << 12;
    int prow0 = pc * CHK + w * 32;       // wave's 32 p-rows

    // A-side fragments (resident for the whole kernel).
    size_t ar = (size_t)(base + prow0 + l15) * 4 + lhi;
    short8v a0  = __builtin_bit_cast(short8v, FA[ar]);
    short8v a1  = __builtin_bit_cast(short8v, FA[ar + 64]);     // +16 rows
    short8v sa0 = __builtin_bit_cast(short8v, SA[ar]);
    short8v sa1 = __builtin_bit_cast(short8v, SA[ar + 64]);
    float hp0[4], hp1[4];
#pragma unroll
    for (int r = 0; r < 4; ++r) {
        hp0[r] = H[base + prow0 + lhi * 4 + r];
        hp1[r] = H[base + prow0 + 16 + lhi * 4 + r];
    }

    float accP = 0.f;   // plain tiles (doubled at the end)
    float accD = 0.f;   // diagonal-chunk tiles (explicit 2/1/0 weights)

#pragma unroll
    for (int jj = 0; jj < 8; ++jj) {
        if (diagblk && jj < 2 * w) continue;   // q-tile fully below both frags
        int qrow0 = qc * CHK + jj * 16;
        size_t br = (size_t)(base + qrow0 + l15) * 4 + lhi;
        short8v bf  = __builtin_bit_cast(short8v, FB[br]);
        short8v sbf = __builtin_bit_cast(short8v, SB[br]);
        float hq = H[base + qrow0 + l15];

        f32x4 cf0 = {0.f, 0.f, 0.f, 0.f};
        f32x4 cf1 = {0.f, 0.f, 0.f, 0.f};
        f32x4 cs0 = {0.f, 0.f, 0.f, 0.f};
        f32x4 cs1 = {0.f, 0.f, 0.f, 0.f};
        cf0 = __builtin_amdgcn_mfma_f32_16x16x32_bf16(a0, bf, cf0, 0, 0, 0);
        cf1 = __builtin_amdgcn_mfma_f32_16x16x32_bf16(a1, bf, cf1, 0, 0, 0);
        cs0 = __builtin_amdgcn_mfma_f32_16x16x32_bf16(sa0, sbf, cs0, 0, 0, 0);
        cs1 = __builtin_amdgcn_mfma_f32_16x16x32_bf16(sa1, sbf, cs1, 0, 0, 0);

        if (!diagblk) {
#pragma unroll
            for (int r = 0; r < 4; ++r) {
                accP = fmaf(EXPFN(cf0[r] + (hp0[r] + hq)), cs0[r], accP);
                accP = fmaf(EXPFN(cf1[r] + (hp1[r] + hq)), cs1[r], accP);
            }
        } else {
            int qgb = qrow0 + l15;               // q index within batch
            int pgb = prow0 + lhi * 4;           // + r (frag0); +16 for frag1
#pragma unroll
            for (int r = 0; r < 4; ++r) {
                float w0 = EXPFN(cf0[r] + (hp0[r] + hq));
                int pg0 = pgb + r;
                float f0 = (qgb > pg0) ? 2.0f : ((qgb == pg0) ? 1.0f : 0.0f);
                accD = fmaf(w0 * f0, cs0[r], accD);
                float w1 = EXPFN(cf1[r] + (hp1[r] + hq));
                int pg1 = pg0 + 16;
                float f1 = (qgb > pg1) ? 2.0f : ((qgb == pg1) ? 1.0f : 0.0f);
                accD = fmaf(w1 * f1, cs1[r], accD);
            }
        }
    }

    float acc_all = 2.0f * accP + accD;
#pragma unroll
    for (int off = 32; off > 0; off >>= 1)
        acc_all += __shfl_down(acc_all, off, 64);
    if ((t & 63) == 0) wsum[t >> 6] = acc_all;
    __syncthreads();
    if (t == 0) {
        part[n * NBLK3 + blockIdx.x] =
            (wsum[0] + wsum[1]) + (wsum[2] + wsum[3]);
    }
}

// Final reduction: 2112 partials -> out[0], single block, no atomics.
__global__ __launch_bounds__(256) void crf_reduce(const float* __restrict__ part,
                                                  float* __restrict__ out) {
    __shared__ float wsum[BLK / 64];
    int t = threadIdx.x;
    float s = 0.f;
#pragma unroll
    for (int i = 0; i < 9; ++i) {
        int idx = t + i * BLK;
        if (idx < NPART) s += part[idx];
    }
#pragma unroll
    for (int off = 32; off > 0; off >>= 1)
        s += __shfl_down(s, off, 64);
    if ((t & 63) == 0) wsum[t >> 6] = s;
    __syncthreads();
    if (t == 0) {
        float tot = (wsum[0] + wsum[1]) + (wsum[2] + wsum[3]);
        // loss = WEIGHT * (-sum / n) = -1e-7/4 * sum
        out[0] = tot * (-2.5e-8f);
    }
}

extern "C" void kernel_launch(void* const* d_in, const int* in_sizes, int n_in,
                              void* d_out, int out_size, void* d_ws, size_t ws_size,
                              hipStream_t stream) {
    const float* images = (const float*)d_in[0];
    const float* segs   = (const float*)d_in[1];
    float* out = (float*)d_out;
    char* ws = (char*)d_ws;
    uint* FA = (uint*)(ws);                     // 16384*64 B = 1 MiB
    uint* FB = (uint*)(ws + (1u << 20));        // 1 MiB
    uint* SA = (uint*)(ws + (2u << 20));        // 1 MiB
    uint* SB = (uint*)(ws + (3u << 20));        // 1 MiB
    float* H = (float*)(ws + (4u << 20));       // 64 KiB
    float* part = (float*)(ws + (4u << 20) + 65536);  // 2112*4 B
    (void)in_sizes; (void)n_in; (void)out_size; (void)ws_size;

    crf_prep<<<dim3(64), dim3(256), 0, stream>>>(images, segs, FA, FB, SA, SB, H);
    crf_pairs<<<dim3(NBLK3, NB), dim3(256), 0, stream>>>(
        (const uint4*)FA, (const uint4*)FB, (const uint4*)SA, (const uint4*)SB, H, part);
    crf_reduce<<<dim3(1), dim3(256), 0, stream>>>(part, out);
}